// Round 1
// baseline (1839.908 us; speedup 1.0000x reference)
//
#include <hip/hip_runtime.h>

// Lure RNN: x' = A x + B1 u + B2 tanh(C2 x + D21 u); y = C1 x' + D11 u + D12 w
// Strategy: latency-bound sequential chain; track pre-activation state
// z~_k = C2 x_k + D21 u_k so per step = tanh (elementwise) + ONE fused GEMM:
//   [x_{k+1}; z~_{k+1}; y_k] = Wfull @ [x_k; w_k; u_k; u_{k+1}]   (192x192)
// 8 blocks x 16 batch, 4 wave-specialized waves, MFMA 16x16x32 bf16 with
// 3-term hi/lo fp32 emulation for state rows (err ~2^-17/step), 1-term for y.
// Weights persistent in VGPR A-fragments; H^T double-buffered in 16KB LDS
// in B-fragment layout; 1 barrier/step; u prefetched 2 steps ahead.

#define NT 2048

typedef __attribute__((ext_vector_type(8))) short short8;
typedef __attribute__((ext_vector_type(4))) float f4;
typedef __attribute__((ext_vector_type(2))) int i2;

union Frag { int i[4]; short8 v; };

__device__ __forceinline__ unsigned rne_bf16(float f) {
  unsigned u = __float_as_uint(f);
  return (u + 0x7FFFu + ((u >> 16) & 1u)) >> 16;
}
__device__ __forceinline__ float bfhi_f(unsigned h) { return __uint_as_float(h << 16); }

__device__ __forceinline__ void split8(const float* x, Frag& hi, Frag& lo) {
#pragma unroll
  for (int p = 0; p < 4; p++) {
    float a = x[2 * p], b = x[2 * p + 1];
    unsigned ha = rne_bf16(a), hb = rne_bf16(b);
    float ra = a - bfhi_f(ha), rb = b - bfhi_f(hb);
    unsigned la = rne_bf16(ra), lb = rne_bf16(rb);
    hi.i[p] = (int)(ha | (hb << 16));
    lo.i[p] = (int)(la | (lb << 16));
  }
}

__device__ __forceinline__ void split4(const float* x, int* hi, int* lo) {
#pragma unroll
  for (int p = 0; p < 2; p++) {
    float a = x[2 * p], b = x[2 * p + 1];
    unsigned ha = rne_bf16(a), hb = rne_bf16(b);
    float ra = a - bfhi_f(ha), rb = b - bfhi_f(hb);
    hi[p] = (int)(ha | (hb << 16));
    lo[p] = (int)(rne_bf16(ra) | (rne_bf16(rb) << 16));
  }
}

__device__ __forceinline__ float ftanh(float x) {
  float e = __expf(2.0f * x);
  return 1.0f - 2.0f * __builtin_amdgcn_rcpf(e + 1.0f);
}

__device__ __forceinline__ f4 mf(const Frag& a, const Frag& b, f4 c) {
  return __builtin_amdgcn_mfma_f32_16x16x32_bf16(a.v, b.v, c, 0, 0, 0);
}

__device__ __forceinline__ void load8u(const float* us, int b, int qq, int k, float* t) {
  const f4* p = (const f4*)(us + ((size_t)b * NT + k) * 32 + 8 * qq);
  f4 a = p[0], c = p[1];
#pragma unroll
  for (int r = 0; r < 4; r++) { t[r] = a[r]; t[4 + r] = c[r]; }
}

__device__ __forceinline__ void wfrag(const float* W, int row0, int c, int lane,
                                      Frag& hi, Frag& lo) {
  const int m = lane & 15, qq = lane >> 4;
  const f4* p = (const f4*)(W + (row0 + m) * 192 + 32 * c + 8 * qq);
  f4 a = p[0], b = p[1];
  float t[8];
#pragma unroll
  for (int r = 0; r < 4; r++) { t[r] = a[r]; t[4 + r] = b[r]; }
  split8(t, hi, lo);
}

// ---- Kernel 1: build Wfull [192 rows x 192 cols] fp32 in workspace ----
// rows 0..63  (x'):  [ A    | B2        | B1        | 0   ]
// rows 64..127(z~'): [ C2A  | C2B2      | C2B1      | D21 ]
// rows128..191(y):   [ C1A  | C1B2+D12  | C1B1+D11  | 0   ]
__global__ void prep_kernel(const float* __restrict__ A, const float* __restrict__ B1,
                            const float* __restrict__ B2, const float* __restrict__ C1,
                            const float* __restrict__ D11, const float* __restrict__ D12,
                            const float* __restrict__ C2, const float* __restrict__ D21,
                            float* __restrict__ Wfull) {
  const int r = blockIdx.x;   // 0..191
  const int c = threadIdx.x;  // 0..191
  float v = 0.f;
  if (c < 64) {
    const int j = c;
    if (r < 64) v = A[r * 64 + j];
    else if (r < 128) { float s = 0.f; for (int l = 0; l < 64; l++) s += C2[(r - 64) * 64 + l] * A[l * 64 + j]; v = s; }
    else { float s = 0.f; for (int l = 0; l < 64; l++) s += C1[(r - 128) * 64 + l] * A[l * 64 + j]; v = s; }
  } else if (c < 128) {
    const int j = c - 64;
    if (r < 64) v = B2[r * 64 + j];
    else if (r < 128) { float s = 0.f; for (int l = 0; l < 64; l++) s += C2[(r - 64) * 64 + l] * B2[l * 64 + j]; v = s; }
    else { float s = 0.f; for (int l = 0; l < 64; l++) s += C1[(r - 128) * 64 + l] * B2[l * 64 + j]; v = s + D12[(r - 128) * 64 + j]; }
  } else if (c < 160) {
    const int j = c - 128;
    if (r < 64) v = B1[r * 32 + j];
    else if (r < 128) { float s = 0.f; for (int l = 0; l < 64; l++) s += C2[(r - 64) * 64 + l] * B1[l * 32 + j]; v = s; }
    else { float s = 0.f; for (int l = 0; l < 64; l++) s += C1[(r - 128) * 64 + l] * B1[l * 32 + j]; v = s + D11[(r - 128) * 32 + j]; }
  } else {
    const int j = c - 160;
    v = (r >= 64 && r < 128) ? D21[(r - 64) * 32 + j] : 0.f;
  }
  Wfull[r * 192 + c] = v;
}

// ---- Kernel 2: sequential recurrence, 8 blocks x 256 threads ----
__global__ __launch_bounds__(256, 1)
void lure_seq(const float* __restrict__ x0, const float* __restrict__ us,
              const float* __restrict__ C2, const float* __restrict__ D21,
              const float* __restrict__ Wfull, float* __restrict__ out) {
  // LDS: 2 buffers x 8 slots x 1KB. slots: 0,1=x_hi c0,c1; 2,3=x_lo; 4,5=w_hi; 6,7=w_lo
  __shared__ int lds[2][8][256];
  const int tid = threadIdx.x;
  const int wave = tid >> 6;
  const int lane = tid & 63;
  const int q = lane >> 4;
  const int nn = lane & 15;
  const int b0 = blockIdx.x * 16;

  // ---- prologue: fill buffer 0 with x_0 and w_0 = tanh(C2 x0 + D21 u0) ----
  {
    const int n = tid >> 4;
    const int f0 = (tid & 15) * 4;
    const int cc = f0 >> 5;
    const int dwi = n * 16 + ((f0 & 31) >> 1);
    const float* xrow = x0 + (b0 + n) * 64;
    float xv[4] = {xrow[f0], xrow[f0 + 1], xrow[f0 + 2], xrow[f0 + 3]};
    int hi[2], lo[2];
    split4(xv, hi, lo);
    lds[0][cc][dwi] = hi[0];     lds[0][cc][dwi + 1] = hi[1];
    lds[0][2 + cc][dwi] = lo[0]; lds[0][2 + cc][dwi + 1] = lo[1];
    float zv[4] = {0.f, 0.f, 0.f, 0.f};
    for (int j = 0; j < 64; j++) {
      float xj = xrow[j];
#pragma unroll
      for (int r = 0; r < 4; r++) zv[r] += C2[(f0 + r) * 64 + j] * xj;
    }
    const float* urow = us + (size_t)(b0 + n) * (NT * 32);
    for (int j = 0; j < 32; j++) {
      float uj = urow[j];
#pragma unroll
      for (int r = 0; r < 4; r++) zv[r] += D21[(f0 + r) * 32 + j] * uj;
    }
#pragma unroll
    for (int r = 0; r < 4; r++) zv[r] = ftanh(zv[r]);
    split4(zv, hi, lo);
    lds[0][4 + cc][dwi] = hi[0]; lds[0][4 + cc][dwi + 1] = hi[1];
    lds[0][6 + cc][dwi] = lo[0]; lds[0][6 + cc][dwi + 1] = lo[1];
  }

  // u fragments: slot0 = u_k(even), slot1 = u_{k+1}
  Frag uh0, ul0, uh1, ul1;
  {
    float t[8];
    load8u(us, b0 + nn, q, 0, t); split8(t, uh0, ul0);
    load8u(us, b0 + nn, q, 1, t); split8(t, uh1, ul1);
  }
  __syncthreads();

  if (wave < 2) {
    // ---- z~ waves: tiles Z0,Z0+1 of rows 64..127; 6 K-chunks; tanh + w writes ----
    const int Z0 = wave * 2;
    Frag WH[2][6], WL[2][6];
#pragma unroll
    for (int t = 0; t < 2; t++)
#pragma unroll
      for (int c = 0; c < 6; c++)
        wfrag(Wfull, 64 + 16 * (Z0 + t), c, lane, WH[t][c], WL[t][c]);

    auto zstep = [&](int k, int rb, Frag& c4h, Frag& c4l, Frag& c5h, Frag& c5l) {
      float ut[8];
      const int kp = (k + 2 < NT) ? k + 2 : NT - 1;
      load8u(us, b0 + nn, q, kp, ut);
      Frag bh[4], bl[4];
#pragma unroll
      for (int c = 0; c < 4; c++) {
        const int sh = (c < 2) ? c : 2 + c;
        const int sl = (c < 2) ? 2 + c : 4 + c;
        bh[c].v = *(const short8*)&lds[rb][sh][nn * 16 + 4 * q];
        bl[c].v = *(const short8*)&lds[rb][sl][nn * 16 + 4 * q];
      }
#pragma unroll
      for (int t = 0; t < 2; t++) {
        f4 s1 = {0.f, 0.f, 0.f, 0.f}, s2 = s1, s3 = s1;
#pragma unroll
        for (int c = 0; c < 4; c++) {
          s1 = mf(WH[t][c], bh[c], s1);
          s2 = mf(WH[t][c], bl[c], s2);
          s3 = mf(WL[t][c], bh[c], s3);
        }
        s1 = mf(WH[t][4], c4h, s1); s2 = mf(WH[t][4], c4l, s2); s3 = mf(WL[t][4], c4h, s3);
        s1 = mf(WH[t][5], c5h, s1); s2 = mf(WH[t][5], c5l, s2); s3 = mf(WL[t][5], c5h, s3);
        float wv[4];
#pragma unroll
        for (int r = 0; r < 4; r++) wv[r] = ftanh(s1[r] + s2[r] + s3[r]);
        int hi[2], lo[2];
        split4(wv, hi, lo);
        const int zt = Z0 + t;
        const int dwi = nn * 16 + 8 * (zt & 1) + 2 * q;
        i2 wh; wh[0] = hi[0]; wh[1] = hi[1];
        i2 wl; wl[0] = lo[0]; wl[1] = lo[1];
        *(i2*)&lds[rb ^ 1][4 + (zt >> 1)][dwi] = wh;
        *(i2*)&lds[rb ^ 1][6 + (zt >> 1)][dwi] = wl;
      }
      split8(ut, c4h, c4l);
      __syncthreads();
    };
    for (int k = 0; k < NT; k += 2) {
      zstep(k, 0, uh0, ul0, uh1, ul1);
      zstep(k + 1, 1, uh1, ul1, uh0, ul0);
    }
  } else {
    // ---- x'/y waves: x' tiles X0,X0+1 (rows 0..63, emu-3) + y tiles (rows 128..191, 1-term) ----
    const int X0 = (wave - 2) * 2;
    Frag WXH[2][5], WXL[2][5], WYH[2][5];
#pragma unroll
    for (int t = 0; t < 2; t++)
#pragma unroll
      for (int c = 0; c < 5; c++) {
        wfrag(Wfull, 16 * (X0 + t), c, lane, WXH[t][c], WXL[t][c]);
        Frag dmy;
        wfrag(Wfull, 128 + 16 * (X0 + t), c, lane, WYH[t][c], dmy);
      }
    auto xstep = [&](int k, int rb, Frag& c4h, Frag& c4l) {
      float ut[8];
      const int kp = (k + 2 < NT) ? k + 2 : NT - 1;
      load8u(us, b0 + nn, q, kp, ut);
      Frag bh[4], bl[4];
#pragma unroll
      for (int c = 0; c < 4; c++) {
        const int sh = (c < 2) ? c : 2 + c;
        const int sl = (c < 2) ? 2 + c : 4 + c;
        bh[c].v = *(const short8*)&lds[rb][sh][nn * 16 + 4 * q];
        bl[c].v = *(const short8*)&lds[rb][sl][nn * 16 + 4 * q];
      }
#pragma unroll
      for (int t = 0; t < 2; t++) {
        f4 s1 = {0.f, 0.f, 0.f, 0.f}, s2 = s1, s3 = s1, sy = s1;
#pragma unroll
        for (int c = 0; c < 4; c++) {
          s1 = mf(WXH[t][c], bh[c], s1);
          s2 = mf(WXH[t][c], bl[c], s2);
          s3 = mf(WXL[t][c], bh[c], s3);
          sy = mf(WYH[t][c], bh[c], sy);
        }
        s1 = mf(WXH[t][4], c4h, s1);
        s2 = mf(WXH[t][4], c4l, s2);
        s3 = mf(WXL[t][4], c4h, s3);
        sy = mf(WYH[t][4], c4h, sy);
        float xv[4];
#pragma unroll
        for (int r = 0; r < 4; r++) xv[r] = s1[r] + s2[r] + s3[r];
        int hi[2], lo[2];
        split4(xv, hi, lo);
        const int xt = X0 + t;
        const int dwi = nn * 16 + 8 * (xt & 1) + 2 * q;
        i2 wh; wh[0] = hi[0]; wh[1] = hi[1];
        i2 wl; wl[0] = lo[0]; wl[1] = lo[1];
        *(i2*)&lds[rb ^ 1][(xt >> 1)][dwi] = wh;
        *(i2*)&lds[rb ^ 1][2 + (xt >> 1)][dwi] = wl;
        float* yp = out + ((size_t)(b0 + nn) * NT + k) * 64 + 16 * xt + 4 * q;
        *(f4*)yp = sy;
      }
      split8(ut, c4h, c4l);
      __syncthreads();
    };
    for (int k = 0; k < NT; k += 2) {
      xstep(k, 0, uh0, ul0);
      xstep(k + 1, 1, uh1, ul1);
    }
  }
}

extern "C" void kernel_launch(void* const* d_in, const int* in_sizes, int n_in,
                              void* d_out, int out_size, void* d_ws, size_t ws_size,
                              hipStream_t stream) {
  const float* x0  = (const float*)d_in[0];
  const float* us  = (const float*)d_in[1];
  const float* A   = (const float*)d_in[2];
  const float* B1  = (const float*)d_in[3];
  const float* B2  = (const float*)d_in[4];
  const float* C1  = (const float*)d_in[5];
  const float* D11 = (const float*)d_in[6];
  const float* D12 = (const float*)d_in[7];
  const float* C2  = (const float*)d_in[8];
  const float* D21 = (const float*)d_in[9];
  float* Wfull = (float*)d_ws;  // 192*192*4 = 147456 bytes
  float* out = (float*)d_out;

  prep_kernel<<<dim3(192), dim3(192), 0, stream>>>(A, B1, B2, C1, D11, D12, C2, D21, Wfull);
  lure_seq<<<dim3(8), dim3(256), 0, stream>>>(x0, us, C2, D21, Wfull, out);
}

// Round 3
// 1539.917 us; speedup vs baseline: 1.1948x; 1.1948x over previous
//
#include <hip/hip_runtime.h>

// Lure RNN, latency-bound sequential chain. Per step: tanh (elementwise) +
// one fused 192x192 GEMM on [x; w; u_k; u_{k+1}] via MFMA 16x16x32 bf16,
// 3-term hi/lo fp32 emulation for state rows, 1-term for y rows.
// R3 = R2 with the bf16 pack helper fixed (no __floats2bfloat162_rn in ROCm):
//  - LDS fragment layout [group][batch][dword] stride 68 (conflict-free reads/writes)
//  - lgkmcnt-only barrier (raw s_barrier): global loads stay in flight across steps
//  - 4-deep u prefetch pipeline; u pre-split to bf16 hi/lo in d_ws (ws-size-checked)
//  - manual RNE bf16 packing; 6 MFMA accumulation chains for z-waves

#define NT 2048

typedef __attribute__((ext_vector_type(8))) short short8;
typedef __attribute__((ext_vector_type(4))) float f4;
typedef __attribute__((ext_vector_type(2))) int i2;

union Frag { int i[4]; short8 v; };

__device__ __forceinline__ unsigned rne_bf16(float f) {
  unsigned u = __float_as_uint(f);
  return (u + 0x7FFFu + ((u >> 16) & 1u)) >> 16;
}
__device__ __forceinline__ void split2(float a, float b, int& hi, int& lo) {
  unsigned ha = rne_bf16(a), hb = rne_bf16(b);
  float ra = a - __uint_as_float(ha << 16);
  float rb = b - __uint_as_float(hb << 16);
  hi = (int)(ha | (hb << 16));
  lo = (int)(rne_bf16(ra) | (rne_bf16(rb) << 16));
}
__device__ __forceinline__ void split8(const float* x, Frag& hi, Frag& lo) {
#pragma unroll
  for (int p = 0; p < 4; p++) split2(x[2 * p], x[2 * p + 1], hi.i[p], lo.i[p]);
}
__device__ __forceinline__ float ftanh(float x) {
  float e = __expf(2.0f * x);
  return 1.0f - 2.0f * __builtin_amdgcn_rcpf(e + 1.0f);
}
__device__ __forceinline__ f4 mf(const Frag& a, const Frag& b, f4 c) {
  return __builtin_amdgcn_mfma_f32_16x16x32_bf16(a.v, b.v, c, 0, 0, 0);
}
// Barrier with LDS-only drain: keeps global loads (vmcnt) in flight across steps.
__device__ __forceinline__ void lds_barrier() {
  __builtin_amdgcn_s_waitcnt(0xC07F);  // lgkmcnt(0), vmcnt=63, expcnt=7
  __builtin_amdgcn_s_barrier();
}
__device__ __forceinline__ void wfrag(const float* W, int row0, int c, int lane,
                                      Frag& hi, Frag& lo) {
  const int m = lane & 15, qq = lane >> 4;
  const f4* p = (const f4*)(W + (size_t)(row0 + m) * 192 + 32 * c + 8 * qq);
  f4 a = p[0], b = p[1];
  float t[8] = {a[0], a[1], a[2], a[3], b[0], b[1], b[2], b[3]};
  split8(t, hi, lo);
}

// ---- prep: u pre-split (blocks < split_blocks) + Wfull build (last 192 blocks) ----
// Wfull rows 0..63 (x'): [A | B2 | B1 | 0]; 64..127 (z~'): [C2A | C2B2 | C2B1 | D21];
// 128..191 (y): [C1A | C1B2+D12 | C1B1+D11 | 0]
__global__ void prep_all(const float* __restrict__ us,
                         const float* __restrict__ A, const float* __restrict__ B1,
                         const float* __restrict__ B2, const float* __restrict__ C1,
                         const float* __restrict__ D11, const float* __restrict__ D12,
                         const float* __restrict__ C2, const float* __restrict__ D21,
                         float* __restrict__ Wfull,
                         unsigned short* __restrict__ uhi, unsigned short* __restrict__ ulo,
                         int split_blocks) {
  if ((int)blockIdx.x < split_blocks) {
    size_t i = ((size_t)blockIdx.x * 256 + threadIdx.x) * 8;
    const f4* p = (const f4*)(us + i);
    f4 a = p[0], b = p[1];
    float t[8] = {a[0], a[1], a[2], a[3], b[0], b[1], b[2], b[3]};
    Frag hi, lo;
    split8(t, hi, lo);
    *(short8*)(uhi + i) = hi.v;
    *(short8*)(ulo + i) = lo.v;
    return;
  }
  const int r = blockIdx.x - split_blocks;
  const int c = threadIdx.x;
  if (c >= 192) return;
  float v = 0.f;
  if (c < 64) {
    const int j = c;
    if (r < 64) v = A[r * 64 + j];
    else if (r < 128) { float s = 0.f; for (int l = 0; l < 64; l++) s += C2[(r - 64) * 64 + l] * A[l * 64 + j]; v = s; }
    else { float s = 0.f; for (int l = 0; l < 64; l++) s += C1[(r - 128) * 64 + l] * A[l * 64 + j]; v = s; }
  } else if (c < 128) {
    const int j = c - 64;
    if (r < 64) v = B2[r * 64 + j];
    else if (r < 128) { float s = 0.f; for (int l = 0; l < 64; l++) s += C2[(r - 64) * 64 + l] * B2[l * 64 + j]; v = s; }
    else { float s = 0.f; for (int l = 0; l < 64; l++) s += C1[(r - 128) * 64 + l] * B2[l * 64 + j]; v = s + D12[(r - 128) * 64 + j]; }
  } else if (c < 160) {
    const int j = c - 128;
    if (r < 64) v = B1[r * 32 + j];
    else if (r < 128) { float s = 0.f; for (int l = 0; l < 64; l++) s += C2[(r - 64) * 64 + l] * B1[l * 32 + j]; v = s; }
    else { float s = 0.f; for (int l = 0; l < 64; l++) s += C1[(r - 128) * 64 + l] * B1[l * 32 + j]; v = s + D11[(r - 128) * 32 + j]; }
  } else {
    const int j = c - 160;
    v = (r >= 64 && r < 128) ? D21[(r - 64) * 32 + j] : 0.f;
  }
  Wfull[r * 192 + c] = v;
}

// ---- sequential recurrence: 8 blocks x 256 threads, 4 specialized waves ----
// LDS slot layout: [g:4][n:16][d:4] dwords, group stride 68 (4-dword pad).
// slots: 0,1 = x_hi c0,c1; 2,3 = x_lo; 4,5 = w_hi; 6,7 = w_lo.
template <bool PRE>
__global__ __launch_bounds__(256, 1)
void lure_seq(const float* __restrict__ x0, const float* __restrict__ us,
              const float* __restrict__ C2, const float* __restrict__ D21,
              const float* __restrict__ Wfull,
              const unsigned short* __restrict__ uhi_g,
              const unsigned short* __restrict__ ulo_g,
              float* __restrict__ out) {
  __shared__ int lds[2][8][272];
  const int tid = threadIdx.x;
  const int wave = tid >> 6;
  const int lane = tid & 63;
  const int q = lane >> 4;
  const int nn = lane & 15;
  const int b0 = blockIdx.x * 16;
  const int ro = q * 68 + nn * 4;  // b128 read offset (conflict-free: 2 lanes/bank)

  // ---- prologue: x_0 and w_0 = tanh(C2 x0 + D21 u0) into buffer 0 ----
  {
    const int n = tid >> 4;
    const int f0 = (tid & 15) * 4;
    const int cc = f0 >> 5;
    const int g = (f0 & 31) >> 3;
    const int d = (f0 & 7) >> 1;  // 0 or 2
    const int idx = g * 68 + n * 4 + d;
    const float* xrow = x0 + (b0 + n) * 64;
    float xv[4] = {xrow[f0], xrow[f0 + 1], xrow[f0 + 2], xrow[f0 + 3]};
    int h0, l0, h1, l1;
    split2(xv[0], xv[1], h0, l0);
    split2(xv[2], xv[3], h1, l1);
    lds[0][cc][idx] = h0;     lds[0][cc][idx + 1] = h1;
    lds[0][2 + cc][idx] = l0; lds[0][2 + cc][idx + 1] = l1;
    float zv[4] = {0.f, 0.f, 0.f, 0.f};
    for (int j = 0; j < 64; j++) {
      float xj = xrow[j];
#pragma unroll
      for (int r = 0; r < 4; r++) zv[r] += C2[(f0 + r) * 64 + j] * xj;
    }
    const float* urow = us + (size_t)(b0 + n) * (NT * 32);
    for (int j = 0; j < 32; j++) {
      float uj = urow[j];
#pragma unroll
      for (int r = 0; r < 4; r++) zv[r] += D21[(f0 + r) * 32 + j] * uj;
    }
#pragma unroll
    for (int r = 0; r < 4; r++) zv[r] = ftanh(zv[r]);
    split2(zv[0], zv[1], h0, l0);
    split2(zv[2], zv[3], h1, l1);
    lds[0][4 + cc][idx] = h0; lds[0][4 + cc][idx + 1] = h1;
    lds[0][6 + cc][idx] = l0; lds[0][6 + cc][idx + 1] = l1;
  }

  // ---- u fragment pipeline ----
  Frag uh[4], ul[4];
  f4 ra0[4], ra1[4];
  const unsigned short* ph = nullptr;
  const unsigned short* pl = nullptr;
  const float* pu = nullptr;
  if constexpr (PRE) {
    ph = uhi_g + ((size_t)(b0 + nn) * NT) * 32 + 8 * q;
    pl = ulo_g + ((size_t)(b0 + nn) * NT) * 32 + 8 * q;
#pragma unroll
    for (int j = 0; j < 4; j++) {
      uh[j].v = *(const short8*)(ph + j * 32);
      ul[j].v = *(const short8*)(pl + j * 32);
    }
  } else {
    pu = us + ((size_t)(b0 + nn) * NT) * 32 + 8 * q;
#pragma unroll
    for (int j = 0; j < 2; j++) {
      const f4* p = (const f4*)(pu + j * 32);
      f4 a = p[0], b = p[1];
      float t[8] = {a[0], a[1], a[2], a[3], b[0], b[1], b[2], b[3]};
      split8(t, uh[j], ul[j]);
    }
#pragma unroll
    for (int j = 2; j <= 5; j++) {
      const f4* p = (const f4*)(pu + j * 32);
      ra0[j & 3] = p[0];
      ra1[j & 3] = p[1];
    }
  }
  lds_barrier();

  if (wave < 2) {
    // ---- z~ waves: rows 64..127; 6 K-chunks, 3-term emu; tanh + w writes ----
    const int Z0 = wave * 2;
    Frag WH[2][6], WL[2][6];
#pragma unroll
    for (int t = 0; t < 2; t++)
#pragma unroll
      for (int c = 0; c < 6; c++)
        wfrag(Wfull, 64 + 16 * (Z0 + t), c, lane, WH[t][c], WL[t][c]);

    auto zstep = [&](int kk, int uu) {
      const int rb = uu & 1;
      Frag bh[4], bl[4];
#pragma unroll
      for (int c = 0; c < 4; c++) {
        const int sh = (c < 2) ? c : 2 + c;  // 0,1,4,5
        bh[c].v = *(const short8*)&lds[rb][sh][ro];
        bl[c].v = *(const short8*)&lds[rb][sh + 2][ro];
      }
      const int i4 = PRE ? uu : (uu & 1);
      const int i5 = PRE ? ((uu + 1) & 3) : ((uu + 1) & 1);
#pragma unroll
      for (int t = 0; t < 2; t++) {
        f4 z4 = {0.f, 0.f, 0.f, 0.f};
        f4 s1a = z4, s1b = z4, s2a = z4, s2b = z4, s3a = z4, s3b = z4;
        s1a = mf(WH[t][0], bh[0], s1a); s1b = mf(WH[t][1], bh[1], s1b);
        s2a = mf(WH[t][0], bl[0], s2a); s2b = mf(WH[t][1], bl[1], s2b);
        s3a = mf(WL[t][0], bh[0], s3a); s3b = mf(WL[t][1], bh[1], s3b);
        s1a = mf(WH[t][2], bh[2], s1a); s1b = mf(WH[t][3], bh[3], s1b);
        s2a = mf(WH[t][2], bl[2], s2a); s2b = mf(WH[t][3], bl[3], s2b);
        s3a = mf(WL[t][2], bh[2], s3a); s3b = mf(WL[t][3], bh[3], s3b);
        s1a = mf(WH[t][4], uh[i4], s1a); s1b = mf(WH[t][5], uh[i5], s1b);
        s2a = mf(WH[t][4], ul[i4], s2a); s2b = mf(WH[t][5], ul[i5], s2b);
        s3a = mf(WL[t][4], uh[i4], s3a); s3b = mf(WL[t][5], uh[i5], s3b);
        float wv[4];
#pragma unroll
        for (int r = 0; r < 4; r++)
          wv[r] = ftanh(((s1a[r] + s1b[r]) + (s2a[r] + s2b[r])) + (s3a[r] + s3b[r]));
        int h0, l0, h1, l1;
        split2(wv[0], wv[1], h0, l0);
        split2(wv[2], wv[3], h1, l1);
        const int zt = Z0 + t;
        const int widx = (2 * (zt & 1) + (q >> 1)) * 68 + nn * 4 + 2 * (q & 1);
        i2 wh; wh[0] = h0; wh[1] = h1;
        i2 wl; wl[0] = l0; wl[1] = l1;
        *(i2*)&lds[rb ^ 1][4 + (zt >> 1)][widx] = wh;
        *(i2*)&lds[rb ^ 1][6 + (zt >> 1)][widx] = wl;
      }
      if constexpr (PRE) {
        const int kp = (kk + 4 < NT) ? kk + 4 : NT - 1;
        uh[uu].v = *(const short8*)(ph + (size_t)kp * 32);
        ul[uu].v = *(const short8*)(pl + (size_t)kp * 32);
      } else {
        f4 a = ra0[(uu + 2) & 3], b = ra1[(uu + 2) & 3];
        float t8[8] = {a[0], a[1], a[2], a[3], b[0], b[1], b[2], b[3]};
        split8(t8, uh[uu & 1], ul[uu & 1]);
        const int kp = (kk + 6 < NT) ? kk + 6 : NT - 1;
        const f4* p = (const f4*)(pu + (size_t)kp * 32);
        ra0[(uu + 2) & 3] = p[0];
        ra1[(uu + 2) & 3] = p[1];
      }
      lds_barrier();
    };
    for (int k = 0; k < NT; k += 4) {
      zstep(k, 0); zstep(k + 1, 1); zstep(k + 2, 2); zstep(k + 3, 3);
    }
  } else {
    // ---- x'/y waves: x' rows 0..63 (3-term), y rows 128..191 (1-term) ----
    const int X0 = (wave - 2) * 2;
    Frag WXH[2][5], WXL[2][5], WYH[2][5];
#pragma unroll
    for (int t = 0; t < 2; t++)
#pragma unroll
      for (int c = 0; c < 5; c++) {
        wfrag(Wfull, 16 * (X0 + t), c, lane, WXH[t][c], WXL[t][c]);
        Frag dmy;
        wfrag(Wfull, 128 + 16 * (X0 + t), c, lane, WYH[t][c], dmy);
      }
    float* py0 = out + (size_t)(b0 + nn) * (NT * 64) + 16 * X0 + 4 * q;

    auto xstep = [&](int kk, int uu) {
      const int rb = uu & 1;
      Frag bh[4], bl[4];
#pragma unroll
      for (int c = 0; c < 4; c++) {
        const int sh = (c < 2) ? c : 2 + c;
        bh[c].v = *(const short8*)&lds[rb][sh][ro];
        bl[c].v = *(const short8*)&lds[rb][sh + 2][ro];
      }
      const int i4 = PRE ? uu : (uu & 1);
#pragma unroll
      for (int t = 0; t < 2; t++) {
        f4 z4 = {0.f, 0.f, 0.f, 0.f};
        f4 s1 = z4, s2 = z4, s3 = z4, sy = z4;
#pragma unroll
        for (int c = 0; c < 4; c++) {
          s1 = mf(WXH[t][c], bh[c], s1);
          s2 = mf(WXH[t][c], bl[c], s2);
          s3 = mf(WXL[t][c], bh[c], s3);
          sy = mf(WYH[t][c], bh[c], sy);
        }
        s1 = mf(WXH[t][4], uh[i4], s1);
        s2 = mf(WXH[t][4], ul[i4], s2);
        s3 = mf(WXL[t][4], uh[i4], s3);
        sy = mf(WYH[t][4], uh[i4], sy);
        float xv[4];
#pragma unroll
        for (int r = 0; r < 4; r++) xv[r] = s1[r] + s2[r] + s3[r];
        int h0, l0, h1, l1;
        split2(xv[0], xv[1], h0, l0);
        split2(xv[2], xv[3], h1, l1);
        const int xt = X0 + t;
        const int widx = (2 * (xt & 1) + (q >> 1)) * 68 + nn * 4 + 2 * (q & 1);
        i2 wh; wh[0] = h0; wh[1] = h1;
        i2 wl; wl[0] = l0; wl[1] = l1;
        *(i2*)&lds[rb ^ 1][(xt >> 1)][widx] = wh;
        *(i2*)&lds[rb ^ 1][2 + (xt >> 1)][widx] = wl;
        *(f4*)(py0 + (size_t)kk * 64 + 16 * t) = sy;
      }
      if constexpr (PRE) {
        const int kp = (kk + 4 < NT) ? kk + 4 : NT - 1;
        uh[uu].v = *(const short8*)(ph + (size_t)kp * 32);
        ul[uu].v = *(const short8*)(pl + (size_t)kp * 32);
      } else {
        f4 a = ra0[(uu + 2) & 3], b = ra1[(uu + 2) & 3];
        float t8[8] = {a[0], a[1], a[2], a[3], b[0], b[1], b[2], b[3]};
        split8(t8, uh[uu & 1], ul[uu & 1]);
        const int kp = (kk + 6 < NT) ? kk + 6 : NT - 1;
        const f4* p = (const f4*)(pu + (size_t)kp * 32);
        ra0[(uu + 2) & 3] = p[0];
        ra1[(uu + 2) & 3] = p[1];
      }
      lds_barrier();
    };
    for (int k = 0; k < NT; k += 4) {
      xstep(k, 0); xstep(k + 1, 1); xstep(k + 2, 2); xstep(k + 3, 3);
    }
  }
}

extern "C" void kernel_launch(void* const* d_in, const int* in_sizes, int n_in,
                              void* d_out, int out_size, void* d_ws, size_t ws_size,
                              hipStream_t stream) {
  const float* x0  = (const float*)d_in[0];
  const float* us  = (const float*)d_in[1];
  const float* A   = (const float*)d_in[2];
  const float* B1  = (const float*)d_in[3];
  const float* B2  = (const float*)d_in[4];
  const float* C1  = (const float*)d_in[5];
  const float* D11 = (const float*)d_in[6];
  const float* D12 = (const float*)d_in[7];
  const float* C2  = (const float*)d_in[8];
  const float* D21 = (const float*)d_in[9];
  float* Wfull = (float*)d_ws;                       // 147456 bytes
  const size_t W_BYTES = (size_t)192 * 192 * 4;
  const size_t UVALS = (size_t)128 * NT * 32;        // 8,388,608
  unsigned short* uhi = (unsigned short*)((char*)d_ws + W_BYTES);
  unsigned short* ulo = uhi + UVALS;
  const size_t NEED = W_BYTES + UVALS * 2 * sizeof(unsigned short);
  const bool pre = ws_size >= NEED;
  const int split_blocks = pre ? (int)(UVALS / 8 / 256) : 0;  // 4096
  float* out = (float*)d_out;

  prep_all<<<dim3(split_blocks + 192), dim3(256), 0, stream>>>(
      us, A, B1, B2, C1, D11, D12, C2, D21, Wfull, uhi, ulo, split_blocks);
  if (pre)
    lure_seq<true><<<dim3(8), dim3(256), 0, stream>>>(x0, us, C2, D21, Wfull, uhi, ulo, out);
  else
    lure_seq<false><<<dim3(8), dim3(256), 0, stream>>>(x0, us, C2, D21, Wfull, uhi, ulo, out);
}

// Round 4
// 1334.950 us; speedup vs baseline: 1.3783x; 1.1535x over previous
//
#include <hip/hip_runtime.h>

// Lure RNN, latency-bound sequential chain.
// R4: u-projections precomputed (UU = Wfull[:,128:192]@[u_k;u_{k+1}]) -> seq K=128,
// u enters as fp32 accumulator init (coalesced, prefetched). 8 waves (512 thr),
// 1 output tile per wave, 2 waves/SIMD for latency hiding. 3-term bf16 emulation
// for state rows, 1-term for y. Fallback to R3 4-wave kernel if ws too small.

#define NT 2048

typedef __attribute__((ext_vector_type(8))) short short8;
typedef __attribute__((ext_vector_type(4))) float f4;
typedef __attribute__((ext_vector_type(2))) int i2;

union Frag { int i[4]; short8 v; };

__device__ __forceinline__ unsigned rne_bf16(float f) {
  unsigned u = __float_as_uint(f);
  return (u + 0x7FFFu + ((u >> 16) & 1u)) >> 16;
}
__device__ __forceinline__ void split2(float a, float b, int& hi, int& lo) {
  unsigned ha = rne_bf16(a), hb = rne_bf16(b);
  float ra = a - __uint_as_float(ha << 16);
  float rb = b - __uint_as_float(hb << 16);
  hi = (int)(ha | (hb << 16));
  lo = (int)(rne_bf16(ra) | (rne_bf16(rb) << 16));
}
__device__ __forceinline__ void split8(const float* x, Frag& hi, Frag& lo) {
#pragma unroll
  for (int p = 0; p < 4; p++) split2(x[2 * p], x[2 * p + 1], hi.i[p], lo.i[p]);
}
__device__ __forceinline__ float ftanh(float x) {
  float e = __expf(2.0f * x);
  return 1.0f - 2.0f * __builtin_amdgcn_rcpf(e + 1.0f);
}
__device__ __forceinline__ f4 mf(const Frag& a, const Frag& b, f4 c) {
  return __builtin_amdgcn_mfma_f32_16x16x32_bf16(a.v, b.v, c, 0, 0, 0);
}
// Barrier with LDS-only drain: keeps global loads (vmcnt) in flight across steps.
__device__ __forceinline__ void lds_barrier() {
  __builtin_amdgcn_s_waitcnt(0xC07F);  // lgkmcnt(0), vmcnt=63, expcnt=7
  __builtin_amdgcn_s_barrier();
}
__device__ __forceinline__ void wfrag(const float* W, int row0, int c, int lane,
                                      Frag& hi, Frag& lo) {
  const int m = lane & 15, qq = lane >> 4;
  const f4* p = (const f4*)(W + (size_t)(row0 + m) * 192 + 32 * c + 8 * qq);
  f4 a = p[0], b = p[1];
  float t[8] = {a[0], a[1], a[2], a[3], b[0], b[1], b[2], b[3]};
  split8(t, hi, lo);
}

// ---- prep_w: build Wfull [192 x 192] fp32 ----
// rows 0..63 (x'): [A | B2 | B1 | 0]; 64..127 (z~'): [C2A | C2B2 | C2B1 | D21];
// 128..191 (y): [C1A | C1B2+D12 | C1B1+D11 | 0]
__global__ void prep_w(const float* __restrict__ A, const float* __restrict__ B1,
                       const float* __restrict__ B2, const float* __restrict__ C1,
                       const float* __restrict__ D11, const float* __restrict__ D12,
                       const float* __restrict__ C2, const float* __restrict__ D21,
                       float* __restrict__ Wfull) {
  const int r = blockIdx.x;   // 0..191
  const int c = threadIdx.x;  // 0..191
  float v = 0.f;
  if (c < 64) {
    const int j = c;
    if (r < 64) v = A[r * 64 + j];
    else if (r < 128) { float s = 0.f; for (int l = 0; l < 64; l++) s += C2[(r - 64) * 64 + l] * A[l * 64 + j]; v = s; }
    else { float s = 0.f; for (int l = 0; l < 64; l++) s += C1[(r - 128) * 64 + l] * A[l * 64 + j]; v = s; }
  } else if (c < 128) {
    const int j = c - 64;
    if (r < 64) v = B2[r * 64 + j];
    else if (r < 128) { float s = 0.f; for (int l = 0; l < 64; l++) s += C2[(r - 64) * 64 + l] * B2[l * 64 + j]; v = s; }
    else { float s = 0.f; for (int l = 0; l < 64; l++) s += C1[(r - 128) * 64 + l] * B2[l * 64 + j]; v = s + D12[(r - 128) * 64 + j]; }
  } else if (c < 160) {
    const int j = c - 128;
    if (r < 64) v = B1[r * 32 + j];
    else if (r < 128) { float s = 0.f; for (int l = 0; l < 64; l++) s += C2[(r - 64) * 64 + l] * B1[l * 32 + j]; v = s; }
    else { float s = 0.f; for (int l = 0; l < 64; l++) s += C1[(r - 128) * 64 + l] * B1[l * 32 + j]; v = s + D11[(r - 128) * 32 + j]; }
  } else {
    const int j = c - 160;
    v = (r >= 64 && r < 128) ? D21[(r - 64) * 32 + j] : 0.f;
  }
  Wfull[r * 192 + c] = v;
}

// ---- prep_uu: UU[k][blk][tt:12][lane:64][4] = u-projections in D-fragment order ----
// tt 0..3: z-tile rows 64+16t (K=64: C2B1 u_k + D21 u_{k+1})
// tt 4..7: x-tile rows 16t   (K=32: B1 u_k)
// tt 8..11: y-tile rows 128+16t (K=32: (C1B1+D11) u_k)
__global__ __launch_bounds__(256)
void prep_uu(const float* __restrict__ us, const float* __restrict__ Wfull,
             float* __restrict__ UU) {
  const int blk = blockIdx.x;  // 0..7
  const int kc = blockIdx.y;   // 0..31 (64 k each)
  const int b0 = blk * 16;
  __shared__ float W3[192][68];
  __shared__ float ub[16][68];
  for (int i = threadIdx.x; i < 3072; i += 256) {  // 192 rows x 16 f4
    int row = i >> 4, c4 = (i & 15) * 4;
    *(f4*)&W3[row][c4] = *(const f4*)(Wfull + (size_t)row * 192 + 128 + c4);
  }
  const int lane = threadIdx.x & 63;
  const int sec = threadIdx.x >> 6;  // 0..3
  const int nn = lane & 15, q = lane >> 4;
  const int rz = 64 + 16 * sec + 4 * q;
  const int rx = 16 * sec + 4 * q;
  const int ry = 128 + 16 * sec + 4 * q;
  const int bt = threadIdx.x >> 4, off = (threadIdx.x & 15) * 4;
  for (int k0 = 0; k0 < 64; k0++) {
    const int k = kc * 64 + k0;
    __syncthreads();
    {
      const float* src = us + ((size_t)(b0 + bt) * NT + k) * 32;
      f4 v = (k == NT - 1 && off >= 32) ? *(const f4*)(src + off - 32)
                                        : *(const f4*)(src + off);
      *(f4*)&ub[bt][off] = v;
    }
    __syncthreads();
    float az[4] = {0, 0, 0, 0}, ax[4] = {0, 0, 0, 0}, ay[4] = {0, 0, 0, 0};
    const float* uv = ub[nn];
#pragma unroll 4
    for (int j = 0; j < 32; j++) {
      float u0 = uv[j], u1 = uv[32 + j];
#pragma unroll
      for (int r = 0; r < 4; r++) {
        az[r] += W3[rz + r][j] * u0 + W3[rz + r][32 + j] * u1;
        ax[r] += W3[rx + r][j] * u0;
        ay[r] += W3[ry + r][j] * u0;
      }
    }
    float* dst = UU + ((((size_t)k * 8 + blk) * 12) * 64 + lane) * 4;
    *(f4*)(dst + (size_t)sec * 256) = *(f4*)az;
    *(f4*)(dst + (size_t)(4 + sec) * 256) = *(f4*)ax;
    *(f4*)(dst + (size_t)(8 + sec) * 256) = *(f4*)ay;
  }
}

// ---- sequential recurrence: 8 blocks x 512 threads, 8 waves (1 tile each) ----
// LDS slots: 0,1 = x_hi c0,c1; 2,3 = x_lo; 4,5 = w_hi; 6,7 = w_lo; [4 groups x 68 dw]
__global__ __launch_bounds__(512, 1)
void lure_seq8(const float* __restrict__ x0, const float* __restrict__ us,
               const float* __restrict__ C2, const float* __restrict__ D21,
               const float* __restrict__ Wfull, const float* __restrict__ UU,
               float* __restrict__ out) {
  __shared__ int lds[2][8][272];
  const int tid = threadIdx.x;
  const int wave = tid >> 6;
  const int lane = tid & 63;
  const int q = lane >> 4;
  const int nn = lane & 15;
  const int b0 = blockIdx.x * 16;
  const int ro = q * 68 + nn * 4;
  const size_t KSTRIDE = 8 * 12 * 256;  // floats per k

  // ---- prologue (first 4 waves): x_0 and w_0 into buffer 0 ----
  if (tid < 256) {
    const int n = tid >> 4;
    const int f0 = (tid & 15) * 4;
    const int cc = f0 >> 5;
    const int g = (f0 & 31) >> 3;
    const int d = (f0 & 7) >> 1;
    const int idx = g * 68 + n * 4 + d;
    const float* xrow = x0 + (b0 + n) * 64;
    float xv[4] = {xrow[f0], xrow[f0 + 1], xrow[f0 + 2], xrow[f0 + 3]};
    int h0, l0, h1, l1;
    split2(xv[0], xv[1], h0, l0);
    split2(xv[2], xv[3], h1, l1);
    lds[0][cc][idx] = h0;     lds[0][cc][idx + 1] = h1;
    lds[0][2 + cc][idx] = l0; lds[0][2 + cc][idx + 1] = l1;
    float zv[4] = {0.f, 0.f, 0.f, 0.f};
    for (int j = 0; j < 64; j++) {
      float xj = xrow[j];
#pragma unroll
      for (int r = 0; r < 4; r++) zv[r] += C2[(f0 + r) * 64 + j] * xj;
    }
    const float* urow = us + (size_t)(b0 + n) * (NT * 32);
    for (int j = 0; j < 32; j++) {
      float uj = urow[j];
#pragma unroll
      for (int r = 0; r < 4; r++) zv[r] += D21[(f0 + r) * 32 + j] * uj;
    }
#pragma unroll
    for (int r = 0; r < 4; r++) zv[r] = ftanh(zv[r]);
    split2(zv[0], zv[1], h0, l0);
    split2(zv[2], zv[3], h1, l1);
    lds[0][4 + cc][idx] = h0; lds[0][4 + cc][idx + 1] = h1;
    lds[0][6 + cc][idx] = l0; lds[0][6 + cc][idx + 1] = l1;
  }

  if (wave < 4) {
    // ---- z-wave: tile zt = wave, rows 64+16*zt, 4 K-chunks (x,w), 3-term ----
    const int zt = wave;
    Frag WH[4], WL[4];
#pragma unroll
    for (int c = 0; c < 4; c++) wfrag(Wfull, 64 + 16 * zt, c, lane, WH[c], WL[c]);
    const float* up = UU + (((size_t)blockIdx.x * 12 + zt) * 64 + lane) * 4;
    f4 uz[4];
#pragma unroll
    for (int d = 0; d < 4; d++) uz[d] = *(const f4*)(up + (size_t)d * KSTRIDE);
    const int widx = (2 * (zt & 1) + (q >> 1)) * 68 + nn * 4 + 2 * (q & 1);
    const int sh = 4 + (zt >> 1), sl = 6 + (zt >> 1);
    lds_barrier();

    auto zstep = [&](int kk, int d) {
      const int rb = kk & 1;
      Frag bh[4], bl[4];
#pragma unroll
      for (int c = 0; c < 4; c++) {
        const int s = (c < 2) ? c : 2 + c;
        bh[c].v = *(const short8*)&lds[rb][s][ro];
        bl[c].v = *(const short8*)&lds[rb][s + 2][ro];
      }
      f4 s1 = uz[d];
      f4 s2 = {0.f, 0.f, 0.f, 0.f}, s3 = s2;
#pragma unroll
      for (int c = 0; c < 4; c++) {
        s1 = mf(WH[c], bh[c], s1);
        s2 = mf(WH[c], bl[c], s2);
        s3 = mf(WL[c], bh[c], s3);
      }
      const int kp = (kk + 4 < NT) ? kk + 4 : NT - 1;
      uz[d] = *(const f4*)(up + (size_t)kp * KSTRIDE);
      float wv[4];
#pragma unroll
      for (int r = 0; r < 4; r++) wv[r] = ftanh(s1[r] + s2[r] + s3[r]);
      int h0, l0, h1, l1;
      split2(wv[0], wv[1], h0, l0);
      split2(wv[2], wv[3], h1, l1);
      i2 wh; wh[0] = h0; wh[1] = h1;
      i2 wl; wl[0] = l0; wl[1] = l1;
      *(i2*)&lds[rb ^ 1][sh][widx] = wh;
      *(i2*)&lds[rb ^ 1][sl][widx] = wl;
      lds_barrier();
    };
    for (int k = 0; k < NT; k += 4) {
      zstep(k, 0); zstep(k + 1, 1); zstep(k + 2, 2); zstep(k + 3, 3);
    }
  } else {
    // ---- x-wave: x'-tile xt rows 16*xt (3-term) + y-tile rows 128+16*xt (1-term) ----
    const int xt = wave - 4;
    Frag WXH[4], WXL[4], WYH[4];
#pragma unroll
    for (int c = 0; c < 4; c++) {
      wfrag(Wfull, 16 * xt, c, lane, WXH[c], WXL[c]);
      Frag dmy;
      wfrag(Wfull, 128 + 16 * xt, c, lane, WYH[c], dmy);
    }
    const float* upx = UU + (((size_t)blockIdx.x * 12 + 4 + xt) * 64 + lane) * 4;
    const float* upy = UU + (((size_t)blockIdx.x * 12 + 8 + xt) * 64 + lane) * 4;
    f4 ux[4], uy[4];
#pragma unroll
    for (int d = 0; d < 4; d++) {
      ux[d] = *(const f4*)(upx + (size_t)d * KSTRIDE);
      uy[d] = *(const f4*)(upy + (size_t)d * KSTRIDE);
    }
    const int widx = (2 * (xt & 1) + (q >> 1)) * 68 + nn * 4 + 2 * (q & 1);
    const int sh = (xt >> 1), sl = 2 + (xt >> 1);
    float* py0 = out + (size_t)(b0 + nn) * (NT * 64) + 16 * xt + 4 * q;
    lds_barrier();

    auto xstep = [&](int kk, int d) {
      const int rb = kk & 1;
      Frag bh[4], bl[4];
#pragma unroll
      for (int c = 0; c < 4; c++) {
        const int s = (c < 2) ? c : 2 + c;
        bh[c].v = *(const short8*)&lds[rb][s][ro];
        bl[c].v = *(const short8*)&lds[rb][s + 2][ro];
      }
      f4 s1 = ux[d], sy = uy[d];
      f4 s2 = {0.f, 0.f, 0.f, 0.f}, s3 = s2;
#pragma unroll
      for (int c = 0; c < 4; c++) {
        s1 = mf(WXH[c], bh[c], s1);
        s2 = mf(WXH[c], bl[c], s2);
        s3 = mf(WXL[c], bh[c], s3);
        sy = mf(WYH[c], bh[c], sy);
      }
      const int kp = (kk + 4 < NT) ? kk + 4 : NT - 1;
      ux[d] = *(const f4*)(upx + (size_t)kp * KSTRIDE);
      uy[d] = *(const f4*)(upy + (size_t)kp * KSTRIDE);
      float xv[4];
#pragma unroll
      for (int r = 0; r < 4; r++) xv[r] = s1[r] + s2[r] + s3[r];
      int h0, l0, h1, l1;
      split2(xv[0], xv[1], h0, l0);
      split2(xv[2], xv[3], h1, l1);
      i2 wh; wh[0] = h0; wh[1] = h1;
      i2 wl; wl[0] = l0; wl[1] = l1;
      *(i2*)&lds[rb ^ 1][sh][widx] = wh;
      *(i2*)&lds[rb ^ 1][sl][widx] = wl;
      *(f4*)(py0 + (size_t)kk * 64) = sy;
      lds_barrier();
    };
    for (int k = 0; k < NT; k += 4) {
      xstep(k, 0); xstep(k + 1, 1); xstep(k + 2, 2); xstep(k + 3, 3);
    }
  }
}

// ---- fallback (ws too small for UU): R3's 4-wave kernel, Wfull only ----
__global__ __launch_bounds__(256, 1)
void lure_seq_fb(const float* __restrict__ x0, const float* __restrict__ us,
                 const float* __restrict__ C2, const float* __restrict__ D21,
                 const float* __restrict__ Wfull, float* __restrict__ out) {
  __shared__ int lds[2][8][272];
  const int tid = threadIdx.x;
  const int wave = tid >> 6;
  const int lane = tid & 63;
  const int q = lane >> 4;
  const int nn = lane & 15;
  const int b0 = blockIdx.x * 16;
  const int ro = q * 68 + nn * 4;
  {
    const int n = tid >> 4;
    const int f0 = (tid & 15) * 4;
    const int cc = f0 >> 5;
    const int g = (f0 & 31) >> 3;
    const int d = (f0 & 7) >> 1;
    const int idx = g * 68 + n * 4 + d;
    const float* xrow = x0 + (b0 + n) * 64;
    float xv[4] = {xrow[f0], xrow[f0 + 1], xrow[f0 + 2], xrow[f0 + 3]};
    int h0, l0, h1, l1;
    split2(xv[0], xv[1], h0, l0);
    split2(xv[2], xv[3], h1, l1);
    lds[0][cc][idx] = h0;     lds[0][cc][idx + 1] = h1;
    lds[0][2 + cc][idx] = l0; lds[0][2 + cc][idx + 1] = l1;
    float zv[4] = {0.f, 0.f, 0.f, 0.f};
    for (int j = 0; j < 64; j++) {
      float xj = xrow[j];
#pragma unroll
      for (int r = 0; r < 4; r++) zv[r] += C2[(f0 + r) * 64 + j] * xj;
    }
    const float* urow = us + (size_t)(b0 + n) * (NT * 32);
    for (int j = 0; j < 32; j++) {
      float uj = urow[j];
#pragma unroll
      for (int r = 0; r < 4; r++) zv[r] += D21[(f0 + r) * 32 + j] * uj;
    }
#pragma unroll
    for (int r = 0; r < 4; r++) zv[r] = ftanh(zv[r]);
    split2(zv[0], zv[1], h0, l0);
    split2(zv[2], zv[3], h1, l1);
    lds[0][4 + cc][idx] = h0; lds[0][4 + cc][idx + 1] = h1;
    lds[0][6 + cc][idx] = l0; lds[0][6 + cc][idx + 1] = l1;
  }
  Frag uh[2], ul[2];
  f4 ra0[4], ra1[4];
  const float* pu = us + ((size_t)(b0 + nn) * NT) * 32 + 8 * q;
#pragma unroll
  for (int j = 0; j < 2; j++) {
    const f4* p = (const f4*)(pu + j * 32);
    f4 a = p[0], b = p[1];
    float t[8] = {a[0], a[1], a[2], a[3], b[0], b[1], b[2], b[3]};
    split8(t, uh[j], ul[j]);
  }
#pragma unroll
  for (int j = 2; j <= 5; j++) {
    const f4* p = (const f4*)(pu + j * 32);
    ra0[j & 3] = p[0];
    ra1[j & 3] = p[1];
  }
  lds_barrier();

  if (wave < 2) {
    const int Z0 = wave * 2;
    Frag WH[2][6], WL[2][6];
#pragma unroll
    for (int t = 0; t < 2; t++)
#pragma unroll
      for (int c = 0; c < 6; c++)
        wfrag(Wfull, 64 + 16 * (Z0 + t), c, lane, WH[t][c], WL[t][c]);
    auto zstep = [&](int kk, int uu) {
      const int rb = uu & 1;
      Frag bh[4], bl[4];
#pragma unroll
      for (int c = 0; c < 4; c++) {
        const int s = (c < 2) ? c : 2 + c;
        bh[c].v = *(const short8*)&lds[rb][s][ro];
        bl[c].v = *(const short8*)&lds[rb][s + 2][ro];
      }
      const int i4 = uu & 1, i5 = (uu + 1) & 1;
#pragma unroll
      for (int t = 0; t < 2; t++) {
        f4 z4 = {0.f, 0.f, 0.f, 0.f};
        f4 s1a = z4, s1b = z4, s2a = z4, s2b = z4, s3a = z4, s3b = z4;
        s1a = mf(WH[t][0], bh[0], s1a); s1b = mf(WH[t][1], bh[1], s1b);
        s2a = mf(WH[t][0], bl[0], s2a); s2b = mf(WH[t][1], bl[1], s2b);
        s3a = mf(WL[t][0], bh[0], s3a); s3b = mf(WL[t][1], bh[1], s3b);
        s1a = mf(WH[t][2], bh[2], s1a); s1b = mf(WH[t][3], bh[3], s1b);
        s2a = mf(WH[t][2], bl[2], s2a); s2b = mf(WH[t][3], bl[3], s2b);
        s3a = mf(WL[t][2], bh[2], s3a); s3b = mf(WL[t][3], bh[3], s3b);
        s1a = mf(WH[t][4], uh[i4], s1a); s1b = mf(WH[t][5], uh[i5], s1b);
        s2a = mf(WH[t][4], ul[i4], s2a); s2b = mf(WH[t][5], ul[i5], s2b);
        s3a = mf(WL[t][4], uh[i4], s3a); s3b = mf(WL[t][5], uh[i5], s3b);
        float wv[4];
#pragma unroll
        for (int r = 0; r < 4; r++)
          wv[r] = ftanh(((s1a[r] + s1b[r]) + (s2a[r] + s2b[r])) + (s3a[r] + s3b[r]));
        int h0, l0, h1, l1;
        split2(wv[0], wv[1], h0, l0);
        split2(wv[2], wv[3], h1, l1);
        const int zt = Z0 + t;
        const int widx = (2 * (zt & 1) + (q >> 1)) * 68 + nn * 4 + 2 * (q & 1);
        i2 wh; wh[0] = h0; wh[1] = h1;
        i2 wl; wl[0] = l0; wl[1] = l1;
        *(i2*)&lds[rb ^ 1][4 + (zt >> 1)][widx] = wh;
        *(i2*)&lds[rb ^ 1][6 + (zt >> 1)][widx] = wl;
      }
      f4 a = ra0[(uu + 2) & 3], b = ra1[(uu + 2) & 3];
      float t8[8] = {a[0], a[1], a[2], a[3], b[0], b[1], b[2], b[3]};
      split8(t8, uh[uu & 1], ul[uu & 1]);
      const int kp = (kk + 6 < NT) ? kk + 6 : NT - 1;
      const f4* p = (const f4*)(pu + (size_t)kp * 32);
      ra0[(uu + 2) & 3] = p[0];
      ra1[(uu + 2) & 3] = p[1];
      lds_barrier();
    };
    for (int k = 0; k < NT; k += 4) {
      zstep(k, 0); zstep(k + 1, 1); zstep(k + 2, 2); zstep(k + 3, 3);
    }
  } else {
    const int X0 = (wave - 2) * 2;
    Frag WXH[2][5], WXL[2][5], WYH[2][5];
#pragma unroll
    for (int t = 0; t < 2; t++)
#pragma unroll
      for (int c = 0; c < 5; c++) {
        wfrag(Wfull, 16 * (X0 + t), c, lane, WXH[t][c], WXL[t][c]);
        Frag dmy;
        wfrag(Wfull, 128 + 16 * (X0 + t), c, lane, WYH[t][c], dmy);
      }
    float* py0 = out + (size_t)(b0 + nn) * (NT * 64) + 16 * X0 + 4 * q;
    auto xstep = [&](int kk, int uu) {
      const int rb = uu & 1;
      Frag bh[4], bl[4];
#pragma unroll
      for (int c = 0; c < 4; c++) {
        const int s = (c < 2) ? c : 2 + c;
        bh[c].v = *(const short8*)&lds[rb][s][ro];
        bl[c].v = *(const short8*)&lds[rb][s + 2][ro];
      }
      const int i4 = uu & 1;
#pragma unroll
      for (int t = 0; t < 2; t++) {
        f4 z4 = {0.f, 0.f, 0.f, 0.f};
        f4 s1 = z4, s2 = z4, s3 = z4, sy = z4;
#pragma unroll
        for (int c = 0; c < 4; c++) {
          s1 = mf(WXH[t][c], bh[c], s1);
          s2 = mf(WXH[t][c], bl[c], s2);
          s3 = mf(WXL[t][c], bh[c], s3);
          sy = mf(WYH[t][c], bh[c], sy);
        }
        s1 = mf(WXH[t][4], uh[i4], s1);
        s2 = mf(WXH[t][4], ul[i4], s2);
        s3 = mf(WXL[t][4], uh[i4], s3);
        sy = mf(WYH[t][4], uh[i4], sy);
        float xv[4];
#pragma unroll
        for (int r = 0; r < 4; r++) xv[r] = s1[r] + s2[r] + s3[r];
        int h0, l0, h1, l1;
        split2(xv[0], xv[1], h0, l0);
        split2(xv[2], xv[3], h1, l1);
        const int xt = X0 + t;
        const int widx = (2 * (xt & 1) + (q >> 1)) * 68 + nn * 4 + 2 * (q & 1);
        i2 wh; wh[0] = h0; wh[1] = h1;
        i2 wl; wl[0] = l0; wl[1] = l1;
        *(i2*)&lds[rb ^ 1][(xt >> 1)][widx] = wh;
        *(i2*)&lds[rb ^ 1][2 + (xt >> 1)][widx] = wl;
        *(f4*)(py0 + (size_t)kk * 64 + 16 * t) = sy;
      }
      f4 a = ra0[(uu + 2) & 3], b = ra1[(uu + 2) & 3];
      float t8[8] = {a[0], a[1], a[2], a[3], b[0], b[1], b[2], b[3]};
      split8(t8, uh[uu & 1], ul[uu & 1]);
      const int kp = (kk + 6 < NT) ? kk + 6 : NT - 1;
      const f4* p = (const f4*)(pu + (size_t)kp * 32);
      ra0[(uu + 2) & 3] = p[0];
      ra1[(uu + 2) & 3] = p[1];
      lds_barrier();
    };
    for (int k = 0; k < NT; k += 4) {
      xstep(k, 0); xstep(k + 1, 1); xstep(k + 2, 2); xstep(k + 3, 3);
    }
  }
}

extern "C" void kernel_launch(void* const* d_in, const int* in_sizes, int n_in,
                              void* d_out, int out_size, void* d_ws, size_t ws_size,
                              hipStream_t stream) {
  const float* x0  = (const float*)d_in[0];
  const float* us  = (const float*)d_in[1];
  const float* A   = (const float*)d_in[2];
  const float* B1  = (const float*)d_in[3];
  const float* B2  = (const float*)d_in[4];
  const float* C1  = (const float*)d_in[5];
  const float* D11 = (const float*)d_in[6];
  const float* D12 = (const float*)d_in[7];
  const float* C2  = (const float*)d_in[8];
  const float* D21 = (const float*)d_in[9];
  float* Wfull = (float*)d_ws;  // 147456 bytes
  const size_t W_BYTES = (size_t)192 * 192 * 4;
  float* UU = (float*)((char*)d_ws + W_BYTES);
  const size_t UU_BYTES = (size_t)NT * 8 * 12 * 256 * 4;  // 201.3 MB
  const bool pre = ws_size >= W_BYTES + UU_BYTES;
  float* out = (float*)d_out;

  prep_w<<<dim3(192), dim3(192), 0, stream>>>(A, B1, B2, C1, D11, D12, C2, D21, Wfull);
  if (pre) {
    prep_uu<<<dim3(8, 32), dim3(256), 0, stream>>>(us, Wfull, UU);
    lure_seq8<<<dim3(8), dim3(512), 0, stream>>>(x0, us, C2, D21, Wfull, UU, out);
  } else {
    lure_seq_fb<<<dim3(8), dim3(256), 0, stream>>>(x0, us, C2, D21, Wfull, out);
  }
}